// Round 3
// baseline (1582.328 us; speedup 1.0000x reference)
//
#include <hip/hip_runtime.h>
#include <stdint.h>

#define M_DIM 8192
#define N_DIM 11008
#define K_DIM 4096
#define KP    2048      // K/2 int32 per packed-W row
#define NG    32        // scale groups per row (K/128)

// ---- 256x256 8-wave 8-phase GEMM geometry ----
#define BM 256
#define BN 256
#define BK 64
#define TSTEPS (K_DIM / BK)                 // 64
#define GRID_G ((M_DIM / BM) * (N_DIM / BN))  // 32*43 = 1376, %8==0

typedef __attribute__((ext_vector_type(2))) _Float16 half2v;
typedef __attribute__((ext_vector_type(8))) _Float16 half8;   // MFMA A/B frag
typedef __attribute__((ext_vector_type(4))) float    floatx4; // MFMA C/D frag
typedef __attribute__((ext_vector_type(4))) int      intx4;
typedef __attribute__((ext_vector_type(4))) unsigned uintx4;

#define GLD16(gptr, lptr)                                                        \
    __builtin_amdgcn_global_load_lds(                                            \
        (const __attribute__((address_space(1))) void*)(gptr),                   \
        (__attribute__((address_space(3))) void*)(lptr), 16, 0, 0)

// ---------------- pre-pass 1: X fp32 -> fp16 (unchanged from round 2) ---------
__global__ __launch_bounds__(256)
void cvt_a(const float* __restrict__ X, _Float16* __restrict__ Aw)
{
    const size_t total  = (size_t)M_DIM * K_DIM / 8;
    const size_t stride = (size_t)gridDim.x * 256;
    for (size_t i = (size_t)blockIdx.x * 256 + threadIdx.x; i < total; i += stride) {
        const float* src = X + i * 8;
        floatx4 x0 = *(const floatx4*)src;
        floatx4 x1 = *(const floatx4*)(src + 4);
        uintx4 o;
        o[0] = __builtin_bit_cast(unsigned, __builtin_amdgcn_cvt_pkrtz(x0[0], x0[1]));
        o[1] = __builtin_bit_cast(unsigned, __builtin_amdgcn_cvt_pkrtz(x0[2], x0[3]));
        o[2] = __builtin_bit_cast(unsigned, __builtin_amdgcn_cvt_pkrtz(x1[0], x1[1]));
        o[3] = __builtin_bit_cast(unsigned, __builtin_amdgcn_cvt_pkrtz(x1[2], x1[3]));
        *(uintx4*)(Aw + i * 8) = o;
    }
}

// ---------------- pre-pass 2: W int4 -> fp16 dequant (unchanged) --------------
__global__ __launch_bounds__(256)
void dequant_w(const int* __restrict__ Wp, const float* __restrict__ Sc,
               _Float16* __restrict__ Bw)
{
    const size_t total  = (size_t)N_DIM * (KP / 4);
    const size_t stride = (size_t)gridDim.x * 256;
    const half2v k1032  = {(_Float16)1032.0f, (_Float16)1032.0f};
    for (size_t c = (size_t)blockIdx.x * 256 + threadIdx.x; c < total; c += stride) {
        const int n   = (int)(c >> 9);
        const int kp0 = ((int)c & 511) << 2;
        intx4 p = *(const intx4*)(Wp + (size_t)n * KP + kp0);
        const _Float16 s = (_Float16)Sc[n * NG + (kp0 >> 6)];
        const half2v s2 = {s, s};
        uintx4 o;
#pragma unroll
        for (int i = 0; i < 4; ++i) {
            unsigned v = (unsigned)p[i];
            unsigned u = 0x64006400u | (v & 0xFu) | ((v & 0xF0u) << 12);
            half2v h = __builtin_bit_cast(half2v, u);
            h = (h - k1032) * s2;
            o[i] = __builtin_bit_cast(unsigned, h);
        }
        *(uintx4*)(Bw + (size_t)n * K_DIM + (size_t)kp0 * 2) = o;
    }
}

// ---------------- main GEMM: 256^2 8-wave, 4-phase/K-tile, counted vmcnt ------
// T2 swizzle: LDS tile [256 rows][64 k] fp16, row stride 128B split into 8
// 16B slots. gload_lds dest is linear; the SOURCE 16B-column is pre-swizzled
// slot = (l&7) ^ (l>>3)  (row&7 == l>>3), so LDS[row][slot s] holds global
// 16B-col (s ^ (row&7)). ds_read applies the same XOR: slot = (ks*4+quad) ^
// (l16&7) -> every 16-lane group covers all 8 bank-groups uniformly (8 lanes
// per 4-bank group = b128 optimum; unswizzled was 16 lanes on one group).
__global__ __launch_bounds__(512, 2)
void gemm_f16_256(const _Float16* __restrict__ A, const _Float16* __restrict__ B,
                  float* __restrict__ Out)
{
    __shared__ __align__(16) _Float16 AL[2][BM * BK];   // 2 x 32 KiB
    __shared__ __align__(16) _Float16 BL[2][BN * BK];   // 2 x 32 KiB

    const int tid = threadIdx.x;
    const int l   = tid & 63;
    const int w   = tid >> 6;

    // XCD swizzle (bijective: GRID_G % 8 == 0), bm fastest -> 32 consecutive
    // ids per XCD share one 2 MiB B panel (L2-fits).
    const int b   = blockIdx.x;
    const int swz = (b & 7) * (GRID_G / 8) + (b >> 3);
    const int bm  = swz & 31;    // 0..31
    const int bn  = swz >> 5;    // 0..42

    // ---- staging addressing (per half-tile: 128 rows x 64 k = 16 KiB,
    //      2 gload_lds insts/thread; inst j covers rows (w*2+j)*8 .. +7)
    const int cg = (l & 7) ^ (l >> 3);   // pre-swizzled global 16B column
    const size_t thr = ((size_t)(w * 16 + (l >> 3))) * K_DIM + (size_t)cg * 8;
    const _Float16* Ab = A + (size_t)bm * BM * K_DIM + thr;
    const _Float16* Bb = B + (size_t)bn * BN * K_DIM + thr;
    const int loff = w * 1024;   // fp16 units; inst1 at +512

    // h: 0 = A rows 0-127, 1 = A rows 128-255, 2 = B rows 0-127, 3 = B rows 128-255
#define STG(h, tt, buf) do {                                                     \
        if ((h) < 2) {                                                           \
            const _Float16* _s = Ab + (size_t)(h) * 128 * K_DIM + (size_t)(tt) * BK; \
            GLD16(_s,              &AL[buf][(h) * 8192 + loff]);                 \
            GLD16(_s + 8 * K_DIM,  &AL[buf][(h) * 8192 + loff + 512]);           \
        } else {                                                                 \
            const _Float16* _s = Bb + (size_t)((h) - 2) * 128 * K_DIM + (size_t)(tt) * BK; \
            GLD16(_s,              &BL[buf][((h) - 2) * 8192 + loff]);           \
            GLD16(_s + 8 * K_DIM,  &BL[buf][((h) - 2) * 8192 + loff + 512]);     \
        } } while (0)

    // ---- fragment read addressing (16x16x32 f16, m89/m91 mapping)
    const int l16  = l & 15;
    const int quad = l >> 4;
    const int wm   = w >> 2;    // 0..1 -> 128 rows of C each
    const int wn   = w & 3;     // 0..3 -> 64 cols of C each
    const int swx  = (l16 & 7) << 4;
    const int c0   = ((quad * 16) ^ swx) >> 1;        // ks0, fp16 units
    const int c1   = (((64 + quad * 16)) ^ swx) >> 1; // ks1
    const int arow = (wm * 128 + l16) * 64;
    const int brow = (wn * 64 + l16) * 64;

    floatx4 acc[8][4];
#pragma unroll
    for (int i = 0; i < 8; ++i)
#pragma unroll
        for (int j = 0; j < 4; ++j)
            acc[i][j] = (floatx4){0.f, 0.f, 0.f, 0.f};

    half8 af[4][2], bf[4][2];

    // ---- prologue: tile0 fully + tile1 half0; counted wait for tile0
    STG(0, 0, 0); STG(1, 0, 0); STG(2, 0, 0); STG(3, 0, 0);
    STG(0, 1, 1);
    asm volatile("s_waitcnt vmcnt(2)" ::: "memory");
    __builtin_amdgcn_s_barrier();

    int cur = 0;
    for (int t = 0; t < TSTEPS; ++t) {
        const int nxt = cur ^ 1;
        const _Float16* Ar = &AL[cur][arow];
        const _Float16* Br = &BL[cur][brow];

        // ---- phase 0: read A[0..3], B[0..1]; stage t+1 half1
        if (t + 1 < TSTEPS) STG(1, t + 1, nxt);
#pragma unroll
        for (int mi = 0; mi < 4; ++mi) {
            af[mi][0] = *(const half8*)(Ar + mi * 1024 + c0);
            af[mi][1] = *(const half8*)(Ar + mi * 1024 + c1);
        }
#pragma unroll
        for (int ni = 0; ni < 2; ++ni) {
            bf[ni][0] = *(const half8*)(Br + ni * 1024 + c0);
            bf[ni][1] = *(const half8*)(Br + ni * 1024 + c1);
        }
        __builtin_amdgcn_s_barrier();
        asm volatile("s_waitcnt lgkmcnt(0)" ::: "memory");
        __builtin_amdgcn_s_setprio(1);
#pragma unroll
        for (int mi = 0; mi < 4; ++mi)
#pragma unroll
            for (int ni = 0; ni < 2; ++ni) {
                acc[mi][ni] = __builtin_amdgcn_mfma_f32_16x16x32_f16(af[mi][0], bf[ni][0], acc[mi][ni], 0, 0, 0);
                acc[mi][ni] = __builtin_amdgcn_mfma_f32_16x16x32_f16(af[mi][1], bf[ni][1], acc[mi][ni], 0, 0, 0);
            }
        __builtin_amdgcn_s_setprio(0);
        __builtin_amdgcn_s_barrier();

        // ---- phase 1: read B[2..3]; stage t+1 half2
        if (t + 1 < TSTEPS) STG(2, t + 1, nxt);
#pragma unroll
        for (int ni = 2; ni < 4; ++ni) {
            bf[ni][0] = *(const half8*)(Br + ni * 1024 + c0);
            bf[ni][1] = *(const half8*)(Br + ni * 1024 + c1);
        }
        __builtin_amdgcn_s_barrier();
        asm volatile("s_waitcnt lgkmcnt(0)" ::: "memory");
        __builtin_amdgcn_s_setprio(1);
#pragma unroll
        for (int mi = 0; mi < 4; ++mi)
#pragma unroll
            for (int ni = 2; ni < 4; ++ni) {
                acc[mi][ni] = __builtin_amdgcn_mfma_f32_16x16x32_f16(af[mi][0], bf[ni][0], acc[mi][ni], 0, 0, 0);
                acc[mi][ni] = __builtin_amdgcn_mfma_f32_16x16x32_f16(af[mi][1], bf[ni][1], acc[mi][ni], 0, 0, 0);
            }
        __builtin_amdgcn_s_setprio(0);
        __builtin_amdgcn_s_barrier();

        // ---- phase 2: read A[4..7] (reuse af regs); stage t+1 half3
        if (t + 1 < TSTEPS) STG(3, t + 1, nxt);
#pragma unroll
        for (int mi = 0; mi < 4; ++mi) {
            af[mi][0] = *(const half8*)(Ar + (mi + 4) * 1024 + c0);
            af[mi][1] = *(const half8*)(Ar + (mi + 4) * 1024 + c1);
        }
        __builtin_amdgcn_s_barrier();
        asm volatile("s_waitcnt lgkmcnt(0)" ::: "memory");
        __builtin_amdgcn_s_setprio(1);
#pragma unroll
        for (int mi = 0; mi < 4; ++mi)
#pragma unroll
            for (int ni = 0; ni < 2; ++ni) {
                acc[mi + 4][ni] = __builtin_amdgcn_mfma_f32_16x16x32_f16(af[mi][0], bf[ni][0], acc[mi + 4][ni], 0, 0, 0);
                acc[mi + 4][ni] = __builtin_amdgcn_mfma_f32_16x16x32_f16(af[mi][1], bf[ni][1], acc[mi + 4][ni], 0, 0, 0);
            }
        __builtin_amdgcn_s_setprio(0);
        __builtin_amdgcn_s_barrier();

        // ---- phase 3: MFMA only; then tile-end counted wait
        __builtin_amdgcn_s_setprio(1);
#pragma unroll
        for (int mi = 0; mi < 4; ++mi)
#pragma unroll
            for (int ni = 2; ni < 4; ++ni) {
                acc[mi + 4][ni] = __builtin_amdgcn_mfma_f32_16x16x32_f16(af[mi][0], bf[ni][0], acc[mi + 4][ni], 0, 0, 0);
                acc[mi + 4][ni] = __builtin_amdgcn_mfma_f32_16x16x32_f16(af[mi][1], bf[ni][1], acc[mi + 4][ni], 0, 0, 0);
            }
        __builtin_amdgcn_s_setprio(0);
        __builtin_amdgcn_s_barrier();            // all waves done reading cur
        if (t + 2 < TSTEPS) {
            STG(0, t + 2, cur);                  // cur is free now
            asm volatile("s_waitcnt vmcnt(2)" ::: "memory");   // t+1 landed
        } else if (t + 1 < TSTEPS) {
            asm volatile("s_waitcnt vmcnt(0)" ::: "memory");   // epilogue drain
        }
        __builtin_amdgcn_s_barrier();            // nxt valid for all waves
        cur = nxt;
    }

    // ---- epilogue: C row = quad*4 + reg, col = l16 (m89/m91)
    const int row0 = bm * BM + wm * 128 + quad * 4;
    const int col0 = bn * BN + wn * 64 + l16;
#pragma unroll
    for (int mi = 0; mi < 8; ++mi) {
#pragma unroll
        for (int r = 0; r < 4; ++r) {
            const size_t row = (size_t)(row0 + mi * 16 + r);
            float* orow = Out + row * N_DIM + col0;
#pragma unroll
            for (int ni = 0; ni < 4; ++ni)
                orow[ni * 16] = acc[mi][ni][r];
        }
    }
#undef STG
}

// ---------------- fallback: original fused kernel (ws too small) --------------
__global__ __launch_bounds__(256, 2)
void w4a16_gemm(const float* __restrict__ X, const int* __restrict__ Wp,
                const float* __restrict__ Sc, float* __restrict__ Out)
{
    __shared__ __align__(16) _Float16 Alds[128 * 32];
    __shared__ __align__(16) _Float16 Blds[128 * 32];

    const int tid = threadIdx.x;
    const int bn  = blockIdx.x;
    const int bm  = blockIdx.y;

    const int srow  = tid >> 1;
    const int shalf = tid & 1;

    const float* Ag = X + (size_t)(bm * 128 + srow) * K_DIM + shalf * 16;
    _Float16* Al = Alds + srow * 32 + shalf * 16;

    const int gn = bn * 128 + srow;
    const int* Bg = Wp + (size_t)gn * KP + shalf * 8;
    const float* Srow = Sc + (size_t)gn * NG;
    _Float16* Bl = Blds + srow * 32 + shalf * 16;

    const int lane = tid & 63;
    const int wave = tid >> 6;
    const int wm   = (wave >> 1) * 64;
    const int wn   = (wave & 1) * 64;
    const int l16  = lane & 15;
    const int quad = lane >> 4;

    const _Float16* Ar = Alds + (wm + l16) * 32 + quad * 8;
    const _Float16* Br = Blds + (wn + l16) * 32 + quad * 8;

    floatx4 acc[4][4];
#pragma unroll
    for (int i = 0; i < 4; ++i)
#pragma unroll
        for (int j = 0; j < 4; ++j)
            acc[i][j] = (floatx4){0.f, 0.f, 0.f, 0.f};

    floatx4 ax[4];
#pragma unroll
    for (int i = 0; i < 4; ++i) ax[i] = *(const floatx4*)(Ag + i * 4);
    intx4 bp0 = *(const intx4*)Bg;
    intx4 bp1 = *(const intx4*)(Bg + 4);
    float sc  = Srow[0];

    for (int ks = 0; ks < 128; ++ks) {
        __syncthreads();

        _Float16 ab[16];
#pragma unroll
        for (int i = 0; i < 4; ++i)
#pragma unroll
            for (int j = 0; j < 4; ++j)
                ab[4 * i + j] = (_Float16)ax[i][j];
        ((intx4*)Al)[0] = ((const intx4*)ab)[0];
        ((intx4*)Al)[1] = ((const intx4*)ab)[1];

        const float s8 = sc * 8.0f;
        _Float16 wb[16];
#pragma unroll
        for (int i = 0; i < 4; ++i) {
            unsigned p = (unsigned)bp0[i];
            wb[2 * i + 0] = (_Float16)fmaf((float)(p & 0xFu), sc, -s8);
            wb[2 * i + 1] = (_Float16)fmaf((float)((p >> 4) & 0xFu), sc, -s8);
        }
#pragma unroll
        for (int i = 0; i < 4; ++i) {
            unsigned p = (unsigned)bp1[i];
            wb[8 + 2 * i + 0] = (_Float16)fmaf((float)(p & 0xFu), sc, -s8);
            wb[8 + 2 * i + 1] = (_Float16)fmaf((float)((p >> 4) & 0xFu), sc, -s8);
        }
        ((intx4*)Bl)[0] = ((const intx4*)wb)[0];
        ((intx4*)Bl)[1] = ((const intx4*)wb)[1];

        if (ks + 1 < 128) {
            const float* Agn = Ag + (ks + 1) * 32;
#pragma unroll
            for (int i = 0; i < 4; ++i) ax[i] = *(const floatx4*)(Agn + i * 4);
            const int* Bgn = Bg + (ks + 1) * 16;
            bp0 = *(const intx4*)Bgn;
            bp1 = *(const intx4*)(Bgn + 4);
            sc  = Srow[(ks + 1) >> 2];
        }

        __syncthreads();

        half8 af[4], bfr[4];
#pragma unroll
        for (int i = 0; i < 4; ++i) {
            af[i]  = *(const half8*)(Ar + i * 16 * 32);
            bfr[i] = *(const half8*)(Br + i * 16 * 32);
        }
#pragma unroll
        for (int mi = 0; mi < 4; ++mi)
#pragma unroll
            for (int ni = 0; ni < 4; ++ni)
                acc[mi][ni] = __builtin_amdgcn_mfma_f32_16x16x32_f16(
                    af[mi], bfr[ni], acc[mi][ni], 0, 0, 0);
    }

    const int row0 = bm * 128 + wm + quad * 4;
    const int col0 = bn * 128 + wn + l16;
#pragma unroll
    for (int mi = 0; mi < 4; ++mi)
#pragma unroll
        for (int r = 0; r < 4; ++r) {
            const size_t row = (size_t)(row0 + mi * 16 + r);
            float* orow = Out + row * N_DIM + col0;
#pragma unroll
            for (int ni = 0; ni < 4; ++ni)
                orow[ni * 16] = acc[mi][ni][r];
        }
}

extern "C" void kernel_launch(void* const* d_in, const int* in_sizes, int n_in,
                              void* d_out, int out_size, void* d_ws, size_t ws_size,
                              hipStream_t stream) {
    const float* X   = (const float*)d_in[0];
    const int*   Wp  = (const int*)d_in[1];
    const float* Sc  = (const float*)d_in[2];
    float*       Out = (float*)d_out;

    const size_t A_BYTES = (size_t)M_DIM * K_DIM * sizeof(_Float16);  // 64 MiB
    const size_t B_BYTES = (size_t)N_DIM * K_DIM * sizeof(_Float16);  // 86 MiB

    if (d_ws && ws_size >= A_BYTES + B_BYTES) {
        _Float16* Aw = (_Float16*)d_ws;
        _Float16* Bw = (_Float16*)((char*)d_ws + A_BYTES);
        cvt_a<<<2048, 256, 0, stream>>>(X, Aw);
        dequant_w<<<2048, 256, 0, stream>>>(Wp, Sc, Bw);
        gemm_f16_256<<<dim3(GRID_G), dim3(512), 0, stream>>>(Aw, Bw, Out);
    } else {
        dim3 grid(N_DIM / 128, M_DIM / 128);
        w4a16_gemm<<<grid, dim3(256), 0, stream>>>(X, Wp, Sc, Out);
    }
}

// Round 4
// 1450.184 us; speedup vs baseline: 1.0911x; 1.0911x over previous
//
#include <hip/hip_runtime.h>
#include <stdint.h>

#define M_DIM 8192
#define N_DIM 11008
#define K_DIM 4096
#define KP    2048      // K/2 int32 per packed-W row
#define NG    32        // scale groups per row (K/128)

// ---- 256x256 8-wave GEMM geometry ----
#define BM 256
#define BN 256
#define BK 64
#define TSTEPS (K_DIM / BK)                 // 64
#define GRID_G ((M_DIM / BM) * (N_DIM / BN))  // 32*43 = 1376, %8==0

typedef __attribute__((ext_vector_type(2))) _Float16 half2v;
typedef __attribute__((ext_vector_type(8))) _Float16 half8;   // MFMA A/B frag
typedef __attribute__((ext_vector_type(4))) float    floatx4; // MFMA C/D frag
typedef __attribute__((ext_vector_type(4))) int      intx4;
typedef __attribute__((ext_vector_type(4))) unsigned uintx4;

#define GLD16(gptr, lptr)                                                        \
    __builtin_amdgcn_global_load_lds(                                            \
        (const __attribute__((address_space(1))) void*)(gptr),                   \
        (__attribute__((address_space(3))) void*)(lptr), 16, 0, 0)

// ---------------- pre-pass 1: X fp32 -> fp16 (unchanged) ----------------------
__global__ __launch_bounds__(256)
void cvt_a(const float* __restrict__ X, _Float16* __restrict__ Aw)
{
    const size_t total  = (size_t)M_DIM * K_DIM / 8;
    const size_t stride = (size_t)gridDim.x * 256;
    for (size_t i = (size_t)blockIdx.x * 256 + threadIdx.x; i < total; i += stride) {
        const float* src = X + i * 8;
        floatx4 x0 = *(const floatx4*)src;
        floatx4 x1 = *(const floatx4*)(src + 4);
        uintx4 o;
        o[0] = __builtin_bit_cast(unsigned, __builtin_amdgcn_cvt_pkrtz(x0[0], x0[1]));
        o[1] = __builtin_bit_cast(unsigned, __builtin_amdgcn_cvt_pkrtz(x0[2], x0[3]));
        o[2] = __builtin_bit_cast(unsigned, __builtin_amdgcn_cvt_pkrtz(x1[0], x1[1]));
        o[3] = __builtin_bit_cast(unsigned, __builtin_amdgcn_cvt_pkrtz(x1[2], x1[3]));
        *(uintx4*)(Aw + i * 8) = o;
    }
}

// ---------------- pre-pass 2: W int4 -> fp16 dequant (unchanged) --------------
__global__ __launch_bounds__(256)
void dequant_w(const int* __restrict__ Wp, const float* __restrict__ Sc,
               _Float16* __restrict__ Bw)
{
    const size_t total  = (size_t)N_DIM * (KP / 4);
    const size_t stride = (size_t)gridDim.x * 256;
    const half2v k1032  = {(_Float16)1032.0f, (_Float16)1032.0f};
    for (size_t c = (size_t)blockIdx.x * 256 + threadIdx.x; c < total; c += stride) {
        const int n   = (int)(c >> 9);
        const int kp0 = ((int)c & 511) << 2;
        intx4 p = *(const intx4*)(Wp + (size_t)n * KP + kp0);
        const _Float16 s = (_Float16)Sc[n * NG + (kp0 >> 6)];
        const half2v s2 = {s, s};
        uintx4 o;
#pragma unroll
        for (int i = 0; i < 4; ++i) {
            unsigned v = (unsigned)p[i];
            unsigned u = 0x64006400u | (v & 0xFu) | ((v & 0xF0u) << 12);
            half2v h = __builtin_bit_cast(half2v, u);
            h = (h - k1032) * s2;
            o[i] = __builtin_bit_cast(unsigned, h);
        }
        *(uintx4*)(Bw + (size_t)n * K_DIM + (size_t)kp0 * 2) = o;
    }
}

// ---------------- main GEMM: 256^2 8-wave, deep-slack counted-vmcnt pipeline --
// Round-4 change vs round-3 (which measured 1176 us, MfmaUtil 27%):
//  * ALL of tile t+1's remaining halves staged at phase-0 start (nxt buffer is
//    free from tile start) -> youngest load gets a full K-step of slack before
//    the single tile-end vmcnt(2) (was ~1 phase -> exposed L2/HBM latency).
//  * h0 of t+2 staged at phase-3 start (cur fully read after phase-2 barrier),
//    overlapping phase-3 MFMA. Barriers 10 -> 7 per K-step.
//  * vmcnt(2) at t's end completes the 8 oldest = ALL of t+1 (h0 from t-1's P3
//    + h1..h3 from t's P0), leaving t+2's h0 in flight. Verified 3x.
__global__ __launch_bounds__(512, 2)
void gemm_f16_256(const _Float16* __restrict__ A, const _Float16* __restrict__ B,
                  float* __restrict__ Out)
{
    __shared__ __align__(16) _Float16 AL[2][BM * BK];   // 2 x 32 KiB
    __shared__ __align__(16) _Float16 BL[2][BN * BK];   // 2 x 32 KiB

    const int tid = threadIdx.x;
    const int l   = tid & 63;
    const int w   = tid >> 6;

    // XCD swizzle (bijective: GRID_G % 8 == 0), bm fastest -> 32 consecutive
    // ids per XCD share one 2 MiB B panel (L2-fits); A panels are L3-resident.
    const int b   = blockIdx.x;
    const int swz = (b & 7) * (GRID_G / 8) + (b >> 3);
    const int bm  = swz & 31;    // 0..31
    const int bn  = swz >> 5;    // 0..42

    // ---- staging addressing (per half-tile: 128 rows x 64 k = 16 KiB,
    //      2 gload_lds insts/thread; T2 swizzle via pre-swizzled global column)
    const int cg = (l & 7) ^ (l >> 3);   // pre-swizzled global 16B column
    const size_t thr = ((size_t)(w * 16 + (l >> 3))) * K_DIM + (size_t)cg * 8;
    const _Float16* Ab = A + (size_t)bm * BM * K_DIM + thr;
    const _Float16* Bb = B + (size_t)bn * BN * K_DIM + thr;
    const int loff = w * 1024;   // fp16 units; inst1 at +512

    // h: 0 = A rows 0-127, 1 = A rows 128-255, 2 = B rows 0-127, 3 = B rows 128-255
#define STG(h, tt, buf) do {                                                     \
        if ((h) < 2) {                                                           \
            const _Float16* _s = Ab + (size_t)(h) * 128 * K_DIM + (size_t)(tt) * BK; \
            GLD16(_s,              &AL[buf][(h) * 8192 + loff]);                 \
            GLD16(_s + 8 * K_DIM,  &AL[buf][(h) * 8192 + loff + 512]);           \
        } else {                                                                 \
            const _Float16* _s = Bb + (size_t)((h) - 2) * 128 * K_DIM + (size_t)(tt) * BK; \
            GLD16(_s,              &BL[buf][((h) - 2) * 8192 + loff]);           \
            GLD16(_s + 8 * K_DIM,  &BL[buf][((h) - 2) * 8192 + loff + 512]);     \
        } } while (0)

    // ---- fragment read addressing (16x16x32 f16, m89/m91 mapping + T2 XOR)
    const int l16  = l & 15;
    const int quad = l >> 4;
    const int wm   = w >> 2;    // 0..1 -> 128 rows of C each
    const int wn   = w & 3;     // 0..3 -> 64 cols of C each
    const int swx  = (l16 & 7) << 4;
    const int c0   = ((quad * 16) ^ swx) >> 1;        // ks0, fp16 units
    const int c1   = (((64 + quad * 16)) ^ swx) >> 1; // ks1
    const int arow = (wm * 128 + l16) * 64;
    const int brow = (wn * 64 + l16) * 64;

    floatx4 acc[8][4];
#pragma unroll
    for (int i = 0; i < 8; ++i)
#pragma unroll
        for (int j = 0; j < 4; ++j)
            acc[i][j] = (floatx4){0.f, 0.f, 0.f, 0.f};

    half8 af[4][2], bf[4][2];

    // ---- prologue: tile0 fully + tile1 h0; counted wait for tile0
    STG(0, 0, 0); STG(1, 0, 0); STG(2, 0, 0); STG(3, 0, 0);
    STG(0, 1, 1);
    asm volatile("s_waitcnt vmcnt(2)" ::: "memory");
    __builtin_amdgcn_s_barrier();

    int cur = 0;
    for (int t = 0; t < TSTEPS; ++t) {
        const int nxt = cur ^ 1;
        const _Float16* Ar = &AL[cur][arow];
        const _Float16* Br = &BL[cur][brow];

        // ---- phase 0: stage ALL remaining halves of t+1; read A[0..3], B[0..1]
        if (t + 1 < TSTEPS) { STG(1, t + 1, nxt); STG(2, t + 1, nxt); STG(3, t + 1, nxt); }
#pragma unroll
        for (int mi = 0; mi < 4; ++mi) {
            af[mi][0] = *(const half8*)(Ar + mi * 1024 + c0);
            af[mi][1] = *(const half8*)(Ar + mi * 1024 + c1);
        }
#pragma unroll
        for (int ni = 0; ni < 2; ++ni) {
            bf[ni][0] = *(const half8*)(Br + ni * 1024 + c0);
            bf[ni][1] = *(const half8*)(Br + ni * 1024 + c1);
        }
        __builtin_amdgcn_s_barrier();
        asm volatile("s_waitcnt lgkmcnt(0)" ::: "memory");
        __builtin_amdgcn_s_setprio(1);
#pragma unroll
        for (int mi = 0; mi < 4; ++mi)
#pragma unroll
            for (int ni = 0; ni < 2; ++ni) {
                acc[mi][ni] = __builtin_amdgcn_mfma_f32_16x16x32_f16(af[mi][0], bf[ni][0], acc[mi][ni], 0, 0, 0);
                acc[mi][ni] = __builtin_amdgcn_mfma_f32_16x16x32_f16(af[mi][1], bf[ni][1], acc[mi][ni], 0, 0, 0);
            }
        __builtin_amdgcn_s_setprio(0);
        __builtin_amdgcn_s_barrier();

        // ---- phase 1: read B[2..3]
#pragma unroll
        for (int ni = 2; ni < 4; ++ni) {
            bf[ni][0] = *(const half8*)(Br + ni * 1024 + c0);
            bf[ni][1] = *(const half8*)(Br + ni * 1024 + c1);
        }
        __builtin_amdgcn_s_barrier();
        asm volatile("s_waitcnt lgkmcnt(0)" ::: "memory");
        __builtin_amdgcn_s_setprio(1);
#pragma unroll
        for (int mi = 0; mi < 4; ++mi)
#pragma unroll
            for (int ni = 2; ni < 4; ++ni) {
                acc[mi][ni] = __builtin_amdgcn_mfma_f32_16x16x32_f16(af[mi][0], bf[ni][0], acc[mi][ni], 0, 0, 0);
                acc[mi][ni] = __builtin_amdgcn_mfma_f32_16x16x32_f16(af[mi][1], bf[ni][1], acc[mi][ni], 0, 0, 0);
            }
        __builtin_amdgcn_s_setprio(0);
        __builtin_amdgcn_s_barrier();

        // ---- phase 2: read A[4..7] (reuse af regs)
#pragma unroll
        for (int mi = 0; mi < 4; ++mi) {
            af[mi][0] = *(const half8*)(Ar + (mi + 4) * 1024 + c0);
            af[mi][1] = *(const half8*)(Ar + (mi + 4) * 1024 + c1);
        }
        __builtin_amdgcn_s_barrier();
        asm volatile("s_waitcnt lgkmcnt(0)" ::: "memory");
        __builtin_amdgcn_s_setprio(1);
#pragma unroll
        for (int mi = 0; mi < 4; ++mi)
#pragma unroll
            for (int ni = 0; ni < 2; ++ni) {
                acc[mi + 4][ni] = __builtin_amdgcn_mfma_f32_16x16x32_f16(af[mi][0], bf[ni][0], acc[mi + 4][ni], 0, 0, 0);
                acc[mi + 4][ni] = __builtin_amdgcn_mfma_f32_16x16x32_f16(af[mi][1], bf[ni][1], acc[mi + 4][ni], 0, 0, 0);
            }
        __builtin_amdgcn_s_setprio(0);
        __builtin_amdgcn_s_barrier();   // all waves done reading cur (last ds_reads were phase 2)

        // ---- phase 3: stage t+2 h0 into cur (now free); MFMA only; tile-end wait
        if (t + 2 < TSTEPS) STG(0, t + 2, cur);
        __builtin_amdgcn_s_setprio(1);
#pragma unroll
        for (int mi = 0; mi < 4; ++mi)
#pragma unroll
            for (int ni = 2; ni < 4; ++ni) {
                acc[mi + 4][ni] = __builtin_amdgcn_mfma_f32_16x16x32_f16(af[mi][0], bf[ni][0], acc[mi + 4][ni], 0, 0, 0);
                acc[mi + 4][ni] = __builtin_amdgcn_mfma_f32_16x16x32_f16(af[mi][1], bf[ni][1], acc[mi + 4][ni], 0, 0, 0);
            }
        __builtin_amdgcn_s_setprio(0);
        if (t + 2 < TSTEPS) {
            asm volatile("s_waitcnt vmcnt(2)" ::: "memory");   // all of t+1 landed
        } else if (t + 1 < TSTEPS) {
            asm volatile("s_waitcnt vmcnt(0)" ::: "memory");   // epilogue drain
        }
        __builtin_amdgcn_s_barrier();   // nxt valid for all waves
        cur = nxt;
    }

    // ---- epilogue: C row = quad*4 + reg, col = l16 (m89/m91)
    const int row0 = bm * BM + wm * 128 + quad * 4;
    const int col0 = bn * BN + wn * 64 + l16;
#pragma unroll
    for (int mi = 0; mi < 8; ++mi) {
#pragma unroll
        for (int r = 0; r < 4; ++r) {
            const size_t row = (size_t)(row0 + mi * 16 + r);
            float* orow = Out + row * N_DIM + col0;
#pragma unroll
            for (int ni = 0; ni < 4; ++ni)
                orow[ni * 16] = acc[mi][ni][r];
        }
    }
#undef STG
}

// ---------------- fallback: original fused kernel (ws too small) --------------
__global__ __launch_bounds__(256, 2)
void w4a16_gemm(const float* __restrict__ X, const int* __restrict__ Wp,
                const float* __restrict__ Sc, float* __restrict__ Out)
{
    __shared__ __align__(16) _Float16 Alds[128 * 32];
    __shared__ __align__(16) _Float16 Blds[128 * 32];

    const int tid = threadIdx.x;
    const int bn  = blockIdx.x;
    const int bm  = blockIdx.y;

    const int srow  = tid >> 1;
    const int shalf = tid & 1;

    const float* Ag = X + (size_t)(bm * 128 + srow) * K_DIM + shalf * 16;
    _Float16* Al = Alds + srow * 32 + shalf * 16;

    const int gn = bn * 128 + srow;
    const int* Bg = Wp + (size_t)gn * KP + shalf * 8;
    const float* Srow = Sc + (size_t)gn * NG;
    _Float16* Bl = Blds + srow * 32 + shalf * 16;

    const int lane = tid & 63;
    const int wave = tid >> 6;
    const int wm   = (wave >> 1) * 64;
    const int wn   = (wave & 1) * 64;
    const int l16  = lane & 15;
    const int quad = lane >> 4;

    const _Float16* Ar = Alds + (wm + l16) * 32 + quad * 8;
    const _Float16* Br = Blds + (wn + l16) * 32 + quad * 8;

    floatx4 acc[4][4];
#pragma unroll
    for (int i = 0; i < 4; ++i)
#pragma unroll
        for (int j = 0; j < 4; ++j)
            acc[i][j] = (floatx4){0.f, 0.f, 0.f, 0.f};

    floatx4 ax[4];
#pragma unroll
    for (int i = 0; i < 4; ++i) ax[i] = *(const floatx4*)(Ag + i * 4);
    intx4 bp0 = *(const intx4*)Bg;
    intx4 bp1 = *(const intx4*)(Bg + 4);
    float sc  = Srow[0];

    for (int ks = 0; ks < 128; ++ks) {
        __syncthreads();

        _Float16 ab[16];
#pragma unroll
        for (int i = 0; i < 4; ++i)
#pragma unroll
            for (int j = 0; j < 4; ++j)
                ab[4 * i + j] = (_Float16)ax[i][j];
        ((intx4*)Al)[0] = ((const intx4*)ab)[0];
        ((intx4*)Al)[1] = ((const intx4*)ab)[1];

        const float s8 = sc * 8.0f;
        _Float16 wb[16];
#pragma unroll
        for (int i = 0; i < 4; ++i) {
            unsigned p = (unsigned)bp0[i];
            wb[2 * i + 0] = (_Float16)fmaf((float)(p & 0xFu), sc, -s8);
            wb[2 * i + 1] = (_Float16)fmaf((float)((p >> 4) & 0xFu), sc, -s8);
        }
#pragma unroll
        for (int i = 0; i < 4; ++i) {
            unsigned p = (unsigned)bp1[i];
            wb[8 + 2 * i + 0] = (_Float16)fmaf((float)(p & 0xFu), sc, -s8);
            wb[8 + 2 * i + 1] = (_Float16)fmaf((float)((p >> 4) & 0xFu), sc, -s8);
        }
        ((intx4*)Bl)[0] = ((const intx4*)wb)[0];
        ((intx4*)Bl)[1] = ((const intx4*)wb)[1];

        if (ks + 1 < 128) {
            const float* Agn = Ag + (ks + 1) * 32;
#pragma unroll
            for (int i = 0; i < 4; ++i) ax[i] = *(const floatx4*)(Agn + i * 4);
            const int* Bgn = Bg + (ks + 1) * 16;
            bp0 = *(const intx4*)Bgn;
            bp1 = *(const intx4*)(Bgn + 4);
            sc  = Srow[(ks + 1) >> 2];
        }

        __syncthreads();

        half8 af[4], bfr[4];
#pragma unroll
        for (int i = 0; i < 4; ++i) {
            af[i]  = *(const half8*)(Ar + i * 16 * 32);
            bfr[i] = *(const half8*)(Br + i * 16 * 32);
        }
#pragma unroll
        for (int mi = 0; mi < 4; ++mi)
#pragma unroll
            for (int ni = 0; ni < 4; ++ni)
                acc[mi][ni] = __builtin_amdgcn_mfma_f32_16x16x32_f16(
                    af[mi], bfr[ni], acc[mi][ni], 0, 0, 0);
    }

    const int row0 = bm * 128 + wm + quad * 4;
    const int col0 = bn * 128 + wn + l16;
#pragma unroll
    for (int mi = 0; mi < 4; ++mi)
#pragma unroll
        for (int r = 0; r < 4; ++r) {
            const size_t row = (size_t)(row0 + mi * 16 + r);
            float* orow = Out + row * N_DIM + col0;
#pragma unroll
            for (int ni = 0; ni < 4; ++ni)
                orow[ni * 16] = acc[mi][ni][r];
        }
}

extern "C" void kernel_launch(void* const* d_in, const int* in_sizes, int n_in,
                              void* d_out, int out_size, void* d_ws, size_t ws_size,
                              hipStream_t stream) {
    const float* X   = (const float*)d_in[0];
    const int*   Wp  = (const int*)d_in[1];
    const float* Sc  = (const float*)d_in[2];
    float*       Out = (float*)d_out;

    const size_t A_BYTES = (size_t)M_DIM * K_DIM * sizeof(_Float16);  // 64 MiB
    const size_t B_BYTES = (size_t)N_DIM * K_DIM * sizeof(_Float16);  // 86 MiB

    if (d_ws && ws_size >= A_BYTES + B_BYTES) {
        _Float16* Aw = (_Float16*)d_ws;
        _Float16* Bw = (_Float16*)((char*)d_ws + A_BYTES);
        cvt_a<<<2048, 256, 0, stream>>>(X, Aw);
        dequant_w<<<2048, 256, 0, stream>>>(Wp, Sc, Bw);
        gemm_f16_256<<<dim3(GRID_G), dim3(512), 0, stream>>>(Aw, Bw, Out);
    } else {
        dim3 grid(N_DIM / 128, M_DIM / 128);
        w4a16_gemm<<<grid, dim3(256), 0, stream>>>(X, Wp, Sc, Out);
    }
}

// Round 5
// 1296.061 us; speedup vs baseline: 1.2209x; 1.1189x over previous
//
#include <hip/hip_runtime.h>
#include <stdint.h>

#define M_DIM 8192
#define N_DIM 11008
#define K_DIM 4096
#define KP    2048      // K/2 int32 per packed-W row
#define NG    32        // scale groups per row (K/128)

// ---- 256x256 8-wave GEMM geometry ----
#define BM 256
#define BN 256
#define BK 64
#define TSTEPS (K_DIM / BK)                 // 64
#define GRID_G ((M_DIM / BM) * (N_DIM / BN))  // 32*43 = 1376, %8==0

typedef __attribute__((ext_vector_type(2))) _Float16 half2v;
typedef __attribute__((ext_vector_type(8))) _Float16 half8;   // MFMA A/B frag
typedef __attribute__((ext_vector_type(4))) float    floatx4; // MFMA C/D frag
typedef __attribute__((ext_vector_type(4))) int      intx4;
typedef __attribute__((ext_vector_type(4))) unsigned uintx4;

#define GLD16(gptr, lptr)                                                        \
    __builtin_amdgcn_global_load_lds(                                            \
        (const __attribute__((address_space(1))) void*)(gptr),                   \
        (__attribute__((address_space(3))) void*)(lptr), 16, 0, 0)

// ---------------- pre-pass 1: X fp32 -> fp16 (nt-loads: read-once stream) -----
__global__ __launch_bounds__(256)
void cvt_a(const float* __restrict__ X, _Float16* __restrict__ Aw)
{
    const size_t total  = (size_t)M_DIM * K_DIM / 8;
    const size_t stride = (size_t)gridDim.x * 256;
    for (size_t i = (size_t)blockIdx.x * 256 + threadIdx.x; i < total; i += stride) {
        const float* src = X + i * 8;
        floatx4 x0 = __builtin_nontemporal_load((const floatx4*)src);
        floatx4 x1 = __builtin_nontemporal_load((const floatx4*)(src + 4));
        uintx4 o;
        o[0] = __builtin_bit_cast(unsigned, __builtin_amdgcn_cvt_pkrtz(x0[0], x0[1]));
        o[1] = __builtin_bit_cast(unsigned, __builtin_amdgcn_cvt_pkrtz(x0[2], x0[3]));
        o[2] = __builtin_bit_cast(unsigned, __builtin_amdgcn_cvt_pkrtz(x1[0], x1[1]));
        o[3] = __builtin_bit_cast(unsigned, __builtin_amdgcn_cvt_pkrtz(x1[2], x1[3]));
        *(uintx4*)(Aw + i * 8) = o;   // normal store: want Aw L3-resident for GEMM
    }
}

// ---------------- pre-pass 2: W int4 -> fp16 dequant (nt-load Wp) -------------
__global__ __launch_bounds__(256)
void dequant_w(const int* __restrict__ Wp, const float* __restrict__ Sc,
               _Float16* __restrict__ Bw)
{
    const size_t total  = (size_t)N_DIM * (KP / 4);
    const size_t stride = (size_t)gridDim.x * 256;
    const half2v k1032  = {(_Float16)1032.0f, (_Float16)1032.0f};
    for (size_t c = (size_t)blockIdx.x * 256 + threadIdx.x; c < total; c += stride) {
        const int n   = (int)(c >> 9);
        const int kp0 = ((int)c & 511) << 2;
        intx4 p = __builtin_nontemporal_load((const intx4*)(Wp + (size_t)n * KP + kp0));
        const _Float16 s = (_Float16)Sc[n * NG + (kp0 >> 6)];
        const half2v s2 = {s, s};
        uintx4 o;
#pragma unroll
        for (int i = 0; i < 4; ++i) {
            unsigned v = (unsigned)p[i];
            unsigned u = 0x64006400u | (v & 0xFu) | ((v & 0xF0u) << 12);
            half2v h = __builtin_bit_cast(half2v, u);
            h = (h - k1032) * s2;
            o[i] = __builtin_bit_cast(unsigned, h);
        }
        *(uintx4*)(Bw + (size_t)n * K_DIM + (size_t)kp0 * 2) = o;   // normal store
    }
}

// ---------------- main GEMM: 256^2 8-wave, template-exact smooth pipeline -----
// Round-5 changes vs round-4 (1053 us, MfmaUtil 30%):
//  * Wave->output remap so each phase reads EXACTLY one half-tile:
//      wave-m rows {wm*64..+63} u {128+wm*64..}, wave-n cols {wn*32..} u {128+wn*32..}
//    -> h0,h2 last-read P0; h3 last-read P1; h1 last-read P2.
//  * One half-tile staged per phase (smooth issue, m196):
//      P0:(t+1,h1)->nxt  P1:(t+2,h0)->cur  P2:(t+2,h2)->cur  P3:(t+2,h3)->cur
//    each stage lands right after its region's last-read barrier (verified 3x).
//  * Single counted wait per K-tile: vmcnt(6) = 3 half-tiles in flight, each
//    with >=4 phases of slack (template-exact, m218).
//  * nt-stores for Out: stop the 352 MB write-once stream from evicting the
//    150 MiB A/B set out of L3 (FETCH was 1.5 GB = 10x minimum).
__global__ __launch_bounds__(512, 2)
void gemm_f16_256(const _Float16* __restrict__ A, const _Float16* __restrict__ B,
                  float* __restrict__ Out)
{
    __shared__ __align__(16) _Float16 AL[2][BM * BK];   // 2 x 32 KiB
    __shared__ __align__(16) _Float16 BL[2][BN * BK];   // 2 x 32 KiB

    const int tid = threadIdx.x;
    const int l   = tid & 63;
    const int w   = tid >> 6;

    // XCD swizzle (bijective: GRID_G % 8 == 0), bm fastest.
    const int b   = blockIdx.x;
    const int swz = (b & 7) * (GRID_G / 8) + (b >> 3);
    const int bm  = swz & 31;    // 0..31
    const int bn  = swz >> 5;    // 0..42

    // ---- staging addressing (half-tile: 128 rows x 64 k = 16 KiB, 2 insts/thr)
    const int cg = (l & 7) ^ (l >> 3);   // pre-swizzled global 16B column (T2)
    const size_t thr = ((size_t)(w * 16 + (l >> 3))) * K_DIM + (size_t)cg * 8;
    const _Float16* Ab = A + (size_t)bm * BM * K_DIM + thr;
    const _Float16* Bb = B + (size_t)bn * BN * K_DIM + thr;
    const int loff = w * 1024;   // fp16 units; inst1 at +512

    // h: 0 = A rows 0-127, 1 = A rows 128-255, 2 = B rows 0-127, 3 = B rows 128-255
#define STG(h, tt, buf) do {                                                     \
        if ((h) < 2) {                                                           \
            const _Float16* _s = Ab + (size_t)(h) * 128 * K_DIM + (size_t)(tt) * BK; \
            GLD16(_s,              &AL[buf][(h) * 8192 + loff]);                 \
            GLD16(_s + 8 * K_DIM,  &AL[buf][(h) * 8192 + loff + 512]);           \
        } else {                                                                 \
            const _Float16* _s = Bb + (size_t)((h) - 2) * 128 * K_DIM + (size_t)(tt) * BK; \
            GLD16(_s,              &BL[buf][((h) - 2) * 8192 + loff]);           \
            GLD16(_s + 8 * K_DIM,  &BL[buf][((h) - 2) * 8192 + loff + 512]);     \
        } } while (0)

    // ---- fragment read addressing (16x16x32 f16, m89/m91 mapping + T2 XOR)
    // NEW mapping: A rows for acc[0..3] = wm*64 + mi*16 + l16  (all in h0)
    //              A rows for acc[4..7] = 128 + wm*64 + mi*16 + l16 (h1)
    //              B rows for ni 0..1   = wn*32 + ni*16 + l16  (h2)
    //              B rows for ni 2..3   = 128 + wn*32 + (ni-2)*16 + l16 (h3)
    const int l16  = l & 15;
    const int quad = l >> 4;
    const int wm   = w >> 2;    // 0..1
    const int wn   = w & 3;     // 0..3
    const int swx  = (l16 & 7) << 4;
    const int c0   = ((quad * 16) ^ swx) >> 1;        // ks0, fp16 units
    const int c1   = (((64 + quad * 16)) ^ swx) >> 1; // ks1
    const int arow = (wm * 64 + l16) * 64;            // h0 base rows
    const int brow = (wn * 32 + l16) * 64;            // h2 base rows

    floatx4 acc[8][4];
#pragma unroll
    for (int i = 0; i < 8; ++i)
#pragma unroll
        for (int j = 0; j < 4; ++j)
            acc[i][j] = (floatx4){0.f, 0.f, 0.f, 0.f};

    half8 af[4][2], bf[4][2];

    // ---- prologue: t0 all 4 halves + t1 {h0,h2,h3}; vmcnt(6) -> t0 landed
    STG(0, 0, 0); STG(1, 0, 0); STG(2, 0, 0); STG(3, 0, 0);
    STG(0, 1, 1); STG(2, 1, 1); STG(3, 1, 1);
    asm volatile("s_waitcnt vmcnt(6)" ::: "memory");
    __builtin_amdgcn_s_barrier();

    int cur = 0;
    for (int t = 0; t < TSTEPS; ++t) {
        const int nxt = cur ^ 1;
        const _Float16* Ar = &AL[cur][arow];
        const _Float16* Br = &BL[cur][brow];

        // ---- P0: read af[0..3] (h0), bf[0..1] (h2); stage (t+1,h1)->nxt
#pragma unroll
        for (int mi = 0; mi < 4; ++mi) {
            af[mi][0] = *(const half8*)(Ar + mi * 1024 + c0);
            af[mi][1] = *(const half8*)(Ar + mi * 1024 + c1);
        }
#pragma unroll
        for (int ni = 0; ni < 2; ++ni) {
            bf[ni][0] = *(const half8*)(Br + ni * 1024 + c0);
            bf[ni][1] = *(const half8*)(Br + ni * 1024 + c1);
        }
        if (t + 1 < TSTEPS) STG(1, t + 1, nxt);
        __builtin_amdgcn_s_barrier();
        asm volatile("s_waitcnt lgkmcnt(0)" ::: "memory");
        __builtin_amdgcn_s_setprio(1);
#pragma unroll
        for (int mi = 0; mi < 4; ++mi)
#pragma unroll
            for (int ni = 0; ni < 2; ++ni) {
                acc[mi][ni] = __builtin_amdgcn_mfma_f32_16x16x32_f16(af[mi][0], bf[ni][0], acc[mi][ni], 0, 0, 0);
                acc[mi][ni] = __builtin_amdgcn_mfma_f32_16x16x32_f16(af[mi][1], bf[ni][1], acc[mi][ni], 0, 0, 0);
            }
        __builtin_amdgcn_s_setprio(0);
        __builtin_amdgcn_s_barrier();   // h0,h2 reads complete for ALL waves

        // ---- P1: read bf[2..3] (h3); stage (t+2,h0)->cur (h0 dead since P0)
#pragma unroll
        for (int ni = 2; ni < 4; ++ni) {
            bf[ni][0] = *(const half8*)(Br + 8192 + (ni - 2) * 1024 + c0);
            bf[ni][1] = *(const half8*)(Br + 8192 + (ni - 2) * 1024 + c1);
        }
        if (t + 2 < TSTEPS) STG(0, t + 2, cur);
        __builtin_amdgcn_s_barrier();
        asm volatile("s_waitcnt lgkmcnt(0)" ::: "memory");
        __builtin_amdgcn_s_setprio(1);
#pragma unroll
        for (int mi = 0; mi < 4; ++mi)
#pragma unroll
            for (int ni = 2; ni < 4; ++ni) {
                acc[mi][ni] = __builtin_amdgcn_mfma_f32_16x16x32_f16(af[mi][0], bf[ni][0], acc[mi][ni], 0, 0, 0);
                acc[mi][ni] = __builtin_amdgcn_mfma_f32_16x16x32_f16(af[mi][1], bf[ni][1], acc[mi][ni], 0, 0, 0);
            }
        __builtin_amdgcn_s_setprio(0);
        __builtin_amdgcn_s_barrier();   // h3 reads complete for ALL waves

        // ---- P2: read af[4..7] (h1, reuse af regs); stage (t+2,h2)->cur
#pragma unroll
        for (int mi = 0; mi < 4; ++mi) {
            af[mi][0] = *(const half8*)(Ar + 8192 + mi * 1024 + c0);
            af[mi][1] = *(const half8*)(Ar + 8192 + mi * 1024 + c1);
        }
        if (t + 2 < TSTEPS) STG(2, t + 2, cur);
        __builtin_amdgcn_s_barrier();
        asm volatile("s_waitcnt lgkmcnt(0)" ::: "memory");
        __builtin_amdgcn_s_setprio(1);
#pragma unroll
        for (int mi = 0; mi < 4; ++mi)
#pragma unroll
            for (int ni = 0; ni < 2; ++ni) {
                acc[mi + 4][ni] = __builtin_amdgcn_mfma_f32_16x16x32_f16(af[mi][0], bf[ni][0], acc[mi + 4][ni], 0, 0, 0);
                acc[mi + 4][ni] = __builtin_amdgcn_mfma_f32_16x16x32_f16(af[mi][1], bf[ni][1], acc[mi + 4][ni], 0, 0, 0);
            }
        __builtin_amdgcn_s_setprio(0);
        __builtin_amdgcn_s_barrier();   // h1 reads complete for ALL waves

        // ---- P3: stage (t+2,h3)->cur; MFMA only; single counted wait
        if (t + 2 < TSTEPS) STG(3, t + 2, cur);
        __builtin_amdgcn_s_setprio(1);
#pragma unroll
        for (int mi = 0; mi < 4; ++mi)
#pragma unroll
            for (int ni = 2; ni < 4; ++ni) {
                acc[mi + 4][ni] = __builtin_amdgcn_mfma_f32_16x16x32_f16(af[mi][0], bf[ni][0], acc[mi + 4][ni], 0, 0, 0);
                acc[mi + 4][ni] = __builtin_amdgcn_mfma_f32_16x16x32_f16(af[mi][1], bf[ni][1], acc[mi + 4][ni], 0, 0, 0);
            }
        __builtin_amdgcn_s_setprio(0);
        if (t + 2 < TSTEPS) {
            asm volatile("s_waitcnt vmcnt(6)" ::: "memory");   // all of t+1 landed
        } else if (t + 1 < TSTEPS) {
            asm volatile("s_waitcnt vmcnt(0)" ::: "memory");   // epilogue drain
        }
        __builtin_amdgcn_s_barrier();
        cur = nxt;
    }

    // ---- epilogue: C row = quad*4 + reg, col = l16 (m89/m91); nt-stores
    const int row0 = bm * BM + wm * 64 + quad * 4;
    const int col0 = bn * BN + wn * 32 + l16;
#pragma unroll
    for (int mi = 0; mi < 8; ++mi) {
        const int grow = row0 + (mi & 3) * 16 + (mi >> 2) * 128;
#pragma unroll
        for (int r = 0; r < 4; ++r) {
            float* orow = Out + (size_t)(grow + r) * N_DIM + col0;
#pragma unroll
            for (int ni = 0; ni < 4; ++ni)
                __builtin_nontemporal_store(acc[mi][ni][r],
                                            orow + (ni & 1) * 16 + (ni >> 1) * 128);
        }
    }
#undef STG
}

// ---------------- fallback: original fused kernel (ws too small) --------------
__global__ __launch_bounds__(256, 2)
void w4a16_gemm(const float* __restrict__ X, const int* __restrict__ Wp,
                const float* __restrict__ Sc, float* __restrict__ Out)
{
    __shared__ __align__(16) _Float16 Alds[128 * 32];
    __shared__ __align__(16) _Float16 Blds[128 * 32];

    const int tid = threadIdx.x;
    const int bn  = blockIdx.x;
    const int bm  = blockIdx.y;

    const int srow  = tid >> 1;
    const int shalf = tid & 1;

    const float* Ag = X + (size_t)(bm * 128 + srow) * K_DIM + shalf * 16;
    _Float16* Al = Alds + srow * 32 + shalf * 16;

    const int gn = bn * 128 + srow;
    const int* Bg = Wp + (size_t)gn * KP + shalf * 8;
    const float* Srow = Sc + (size_t)gn * NG;
    _Float16* Bl = Blds + srow * 32 + shalf * 16;

    const int lane = tid & 63;
    const int wave = tid >> 6;
    const int wm   = (wave >> 1) * 64;
    const int wn   = (wave & 1) * 64;
    const int l16  = lane & 15;
    const int quad = lane >> 4;

    const _Float16* Ar = Alds + (wm + l16) * 32 + quad * 8;
    const _Float16* Br = Blds + (wn + l16) * 32 + quad * 8;

    floatx4 acc[4][4];
#pragma unroll
    for (int i = 0; i < 4; ++i)
#pragma unroll
        for (int j = 0; j < 4; ++j)
            acc[i][j] = (floatx4){0.f, 0.f, 0.f, 0.f};

    floatx4 ax[4];
#pragma unroll
    for (int i = 0; i < 4; ++i) ax[i] = *(const floatx4*)(Ag + i * 4);
    intx4 bp0 = *(const intx4*)Bg;
    intx4 bp1 = *(const intx4*)(Bg + 4);
    float sc  = Srow[0];

    for (int ks = 0; ks < 128; ++ks) {
        __syncthreads();

        _Float16 ab[16];
#pragma unroll
        for (int i = 0; i < 4; ++i)
#pragma unroll
            for (int j = 0; j < 4; ++j)
                ab[4 * i + j] = (_Float16)ax[i][j];
        ((intx4*)Al)[0] = ((const intx4*)ab)[0];
        ((intx4*)Al)[1] = ((const intx4*)ab)[1];

        const float s8 = sc * 8.0f;
        _Float16 wb[16];
#pragma unroll
        for (int i = 0; i < 4; ++i) {
            unsigned p = (unsigned)bp0[i];
            wb[2 * i + 0] = (_Float16)fmaf((float)(p & 0xFu), sc, -s8);
            wb[2 * i + 1] = (_Float16)fmaf((float)((p >> 4) & 0xFu), sc, -s8);
        }
#pragma unroll
        for (int i = 0; i < 4; ++i) {
            unsigned p = (unsigned)bp1[i];
            wb[8 + 2 * i + 0] = (_Float16)fmaf((float)(p & 0xFu), sc, -s8);
            wb[8 + 2 * i + 1] = (_Float16)fmaf((float)((p >> 4) & 0xFu), sc, -s8);
        }
        ((intx4*)Bl)[0] = ((const intx4*)wb)[0];
        ((intx4*)Bl)[1] = ((const intx4*)wb)[1];

        if (ks + 1 < 128) {
            const float* Agn = Ag + (ks + 1) * 32;
#pragma unroll
            for (int i = 0; i < 4; ++i) ax[i] = *(const floatx4*)(Agn + i * 4);
            const int* Bgn = Bg + (ks + 1) * 16;
            bp0 = *(const intx4*)Bgn;
            bp1 = *(const intx4*)(Bgn + 4);
            sc  = Srow[(ks + 1) >> 2];
        }

        __syncthreads();

        half8 af[4], bfr[4];
#pragma unroll
        for (int i = 0; i < 4; ++i) {
            af[i]  = *(const half8*)(Ar + i * 16 * 32);
            bfr[i] = *(const half8*)(Br + i * 16 * 32);
        }
#pragma unroll
        for (int mi = 0; mi < 4; ++mi)
#pragma unroll
            for (int ni = 0; ni < 4; ++ni)
                acc[mi][ni] = __builtin_amdgcn_mfma_f32_16x16x32_f16(
                    af[mi], bfr[ni], acc[mi][ni], 0, 0, 0);
    }

    const int row0 = bm * 128 + wm + quad * 4;
    const int col0 = bn * 128 + wn + l16;
#pragma unroll
    for (int mi = 0; mi < 4; ++mi)
#pragma unroll
        for (int r = 0; r < 4; ++r) {
            const size_t row = (size_t)(row0 + mi * 16 + r);
            float* orow = Out + row * N_DIM + col0;
#pragma unroll
            for (int ni = 0; ni < 4; ++ni)
                orow[ni * 16] = acc[mi][ni][r];
        }
}

extern "C" void kernel_launch(void* const* d_in, const int* in_sizes, int n_in,
                              void* d_out, int out_size, void* d_ws, size_t ws_size,
                              hipStream_t stream) {
    const float* X   = (const float*)d_in[0];
    const int*   Wp  = (const int*)d_in[1];
    const float* Sc  = (const float*)d_in[2];
    float*       Out = (float*)d_out;

    const size_t A_BYTES = (size_t)M_DIM * K_DIM * sizeof(_Float16);  // 64 MiB
    const size_t B_BYTES = (size_t)N_DIM * K_DIM * sizeof(_Float16);  // 86 MiB

    if (d_ws && ws_size >= A_BYTES + B_BYTES) {
        _Float16* Aw = (_Float16*)d_ws;
        _Float16* Bw = (_Float16*)((char*)d_ws + A_BYTES);
        cvt_a<<<2048, 256, 0, stream>>>(X, Aw);
        dequant_w<<<2048, 256, 0, stream>>>(Wp, Sc, Bw);
        gemm_f16_256<<<dim3(GRID_G), dim3(512), 0, stream>>>(Aw, Bw, Out);
    } else {
        dim3 grid(N_DIM / 128, M_DIM / 128);
        w4a16_gemm<<<grid, dim3(256), 0, stream>>>(X, Wp, Sc, Out);
    }
}